// Round 3
// baseline (184.124 us; speedup 1.0000x reference)
//
#include <hip/hip_runtime.h>

// Correlation layer, fused single-pass banded-MFMA kernel (gfx950).
// out[b, dy*9+dx, y, x] = sum_c f1[b,c,y,x] * f2[b,c,y+dy-4,x+dx-4]
//
// R12 = R11 with the compile fix (manual RNE pack; __hip_bfloat162 is not
// trivially copyable so __builtin_bit_cast on it fails; m240 says hand-asm
// cvt_pk is a pessimization anyway).
//
// R11: software-pipeline the chunk loop (T14 async-stage split).
// Rationale (rocprof R10): all pipes idle (Mfma 4.6%, VALU 16%, HBM 14%) —
// kernel is latency-serialized per chunk: barrier -> load burst -> full
// memory-latency stall -> convert/write -> barrier -> short compute. Fix:
//  - prefetch chunk ch+1 (f2 tile + f1 fragment) into REGISTERS right after
//    the post-write barrier, before chunk ch's ds_read+MFMA phase; the
//    convert/write at the top of iteration ch+1 then finds data resident.
//  - f1 has ZERO cross-wave reuse (one y-row per wave) -> drop the f1 LDS
//    tile; each lane gathers its 8 channel values directly from global and
//    packs the A-fragment in-register. Saves 10KB LDS + a staging pass.
// Block geometry unchanged from R10 (verified): 512 blocks = 8b x 8yg x 8xg,
// 512 threads, b=id&7 XCD pin, f2 LDS tile 16 rows x 32 cols x 32ch, PXS=20
// bank-balanced layout, banded 2-tile epilogue writes each output once.

namespace {
constexpr int B_ = 8, C_ = 256, H_ = 64, W_ = 128;
constexpr int SIDE = 9, ND = 81, PAD = 4;
constexpr int HW = H_ * W_;
constexpr int KC = 32;                    // channels per LDS chunk
constexpr int NCH = C_ / KC;              // 8 chunks
constexpr int YB = 8;                     // output rows per block
constexpr int RWS = YB + 2 * PAD;         // 16 staged f2 rows
constexpr int XB = 16;                    // output cols per block
constexpr int F2PX = 32;                  // staged f2 cols (XB + 16 band)
constexpr int PXS = KC / 2 + 4;           // 20: ch-pair stride (+4 pad)
}

typedef __attribute__((ext_vector_type(8))) short short8;
typedef __attribute__((ext_vector_type(4))) float float4v;

__device__ __forceinline__ unsigned bf16rne(float f) {
  unsigned u = __float_as_uint(f);
  return (u + 0x7fffu + ((u >> 16) & 1u)) >> 16;
}
__device__ __forceinline__ unsigned packbf2(float lo, float hi) {
  return bf16rne(lo) | (bf16rne(hi) << 16);
}

__global__ __launch_bounds__(512, 2)
void corr_fused(const float* __restrict__ f1, const float* __restrict__ f2,
                float* __restrict__ out) {
  __shared__ __align__(16) unsigned f2s[RWS * F2PX * PXS];  // 40 KB

  const int id = blockIdx.x;
  const int b = id & 7;                   // XCD pin
  const int k = id >> 3;                  // 0..63
  const int xg = k & 7;
  const int yg = k >> 3;
  const int x0 = xg * XB;
  const int y0 = yg * YB;

  const int t = threadIdx.x;
  const int lane = t & 63;
  const int w = t >> 6;                   // wave 0..7 -> y row y0+w
  const int v = lane & 15;                // fragment pixel index
  const int q = lane >> 4;                // k-quad / C-row-group

  // f2 staging geometry: thread t owns ch-pair cp2, col-quad pxq2, rows
  // r0, r0+4, r0+8, r0+12 (u = t + 512*i decomposition collapses to this).
  const int cp2 = t & 15;
  const int pxq2 = (t >> 4) & 7;
  const int r0 = t >> 7;                  // 0..3
  const int xb = x0 - PAD + pxq2 * 4;
  const bool xok = (xb >= 0 && xb <= W_ - 4);

  const float* __restrict__ f1b = f1 + (size_t)b * C_ * HW;
  const float* __restrict__ f2b = f2 + (size_t)b * C_ * HW;

  float4 pa[4], pb[4];                    // prefetched f2 (2 ch x 4 rows)
  float pf1[8];                           // prefetched f1 fragment channels

  auto loadf2 = [&](int c0) {
#pragma unroll
    for (int i = 0; i < 4; ++i) {
      const int ygl = y0 - PAD + r0 + 4 * i;
      float4 va = make_float4(0.f, 0.f, 0.f, 0.f), vb = va;
      if (xok && ygl >= 0 && ygl < H_) {
        const float* p = f2b + ((size_t)(c0 + 2 * cp2) * H_ + ygl) * W_ + xb;
        va = *(const float4*)p;
        vb = *(const float4*)(p + HW);
      }
      pa[i] = va;
      pb[i] = vb;
    }
  };
  auto loadf1 = [&](int c0) {
    const float* p = f1b + ((size_t)(c0 + 8 * q) * H_ + (y0 + w)) * W_ + x0 + v;
#pragma unroll
    for (int j = 0; j < 8; ++j) pf1[j] = p[(size_t)j * HW];
  };

  float4v acc[SIDE][2];
#pragma unroll
  for (int i = 0; i < SIDE; ++i) {
    acc[i][0] = (float4v){0.f, 0.f, 0.f, 0.f};
    acc[i][1] = (float4v){0.f, 0.f, 0.f, 0.f};
  }

  loadf2(0);
  loadf1(0);

#pragma unroll
  for (int ch = 0; ch < NCH; ++ch) {
    if (ch) __syncthreads();              // prior chunk's ds_reads done

    // ---- convert + write prefetched f2 regs -> LDS ----
    {
      unsigned* d0 = &f2s[(size_t)(pxq2 * 4) * PXS + cp2];
#pragma unroll
      for (int i = 0; i < 4; ++i) {
        unsigned* d = d0 + (size_t)(r0 + 4 * i) * F2PX * PXS;
        d[0 * PXS] = packbf2(pa[i].x, pb[i].x);
        d[1 * PXS] = packbf2(pa[i].y, pb[i].y);
        d[2 * PXS] = packbf2(pa[i].z, pb[i].z);
        d[3 * PXS] = packbf2(pa[i].w, pb[i].w);
      }
    }
    // ---- pack A fragment from f1 regs (before prefetch overwrites) ----
    uint4 afu;
    afu.x = packbf2(pf1[0], pf1[1]);
    afu.y = packbf2(pf1[2], pf1[3]);
    afu.z = packbf2(pf1[4], pf1[5]);
    afu.w = packbf2(pf1[6], pf1[7]);
    const short8 af = __builtin_bit_cast(short8, afu);

    __syncthreads();                      // LDS tile visible

    // ---- issue next chunk's global loads (hide under compute) ----
    if (ch + 1 < NCH) {
      loadf2((ch + 1) * KC);
      loadf1((ch + 1) * KC);
    }

    // ---- banded MFMA: one y row per wave, 9 dy x 2 tiles ----
#pragma unroll
    for (int dy = 0; dy < SIDE; ++dy) {
      const unsigned* fp = &f2s[((w + dy) * F2PX + v) * PXS + 4 * q];
      const short8 b0 = __builtin_bit_cast(short8, *(const uint4*)fp);
      const short8 b1 =
          __builtin_bit_cast(short8, *(const uint4*)(fp + 16 * PXS));
      acc[dy][0] =
          __builtin_amdgcn_mfma_f32_16x16x32_bf16(af, b0, acc[dy][0], 0, 0, 0);
      acc[dy][1] =
          __builtin_amdgcn_mfma_f32_16x16x32_bf16(af, b1, acc[dy][1], 0, 0, 0);
    }
  }

  // Epilogue: C/D col n = v, row m = q*4+r. tile0: dx = v-m in [0,8];
  // tile1: dx = v-m+16 in [1,8]. Each output element written exactly once.
  const int y = y0 + w;
  float* outb = out + (size_t)b * ND * HW + (size_t)y * W_ + x0;
#pragma unroll
  for (int dy = 0; dy < SIDE; ++dy) {
#pragma unroll
    for (int r = 0; r < 4; ++r) {
      const int m = q * 4 + r;
      const int dx0 = v - m;
      if (dx0 >= 0 && dx0 <= 8)
        outb[(size_t)(dy * SIDE + dx0) * HW + m] = acc[dy][0][r];
      const int dx1 = v - m + 16;
      if (dx1 <= 8)
        outb[(size_t)(dy * SIDE + dx1) * HW + m] = acc[dy][1][r];
    }
  }
}

extern "C" void kernel_launch(void* const* d_in, const int* in_sizes, int n_in,
                              void* d_out, int out_size, void* d_ws,
                              size_t ws_size, hipStream_t stream) {
  (void)in_sizes; (void)n_in; (void)out_size; (void)d_ws; (void)ws_size;
  const float* f1 = (const float*)d_in[0];
  const float* f2 = (const float*)d_in[1];
  float* out = (float*)d_out;
  corr_fused<<<dim3(512), 512, 0, stream>>>(f1, f2, out);
}

// Round 4
// 182.632 us; speedup vs baseline: 1.0082x; 1.0082x over previous
//
#include <hip/hip_runtime.h>

// Correlation layer, two-pass banded-MFMA with LDS-DMA pipeline (gfx950).
// out[b, dy*9+dx, y, x] = sum_c f1[b,c,y,x] * f2[b,c,y+dy-4,x+dx-4]
//
// R13: R10's blocking + T3/T4 pipeline via global_load_lds double-buffer.
// Rocprof history: R10 (fused, 78us) and R12 (reg-prefetch, 89us) both show
// all pipes idle (Mfma ~4%, VALU ~16%, HBM ~13%) -> latency-serialized chunk
// loop. R12 proved reg-held prefetch costs occupancy (37%->20%). Fix: put
// the prefetch in LDS with zero VGPR cost:
//  - pass 1 cvt_f2 (R9-proven): f2 -> w2 bf16 fragment-ready layout
//    [b][cs][yp][q][xp=144] uint4 (8-ch oct per uint4), 42.5 MB workspace.
//  - pass 2 corr_mfma2: per chunk each wave issues 4x global_load_lds(16B)
//    into a 32KB tile, double-buffered (64KB -> 2 blocks/CU); counted
//    s_waitcnt vmcnt(4) + RAW s_barrier (+sched_barrier(0) fences) so the
//    next tile's DMA stays in flight across barriers (never drain to 0).
//    f1 A-fragment double-buffered in 8 regs/wave (cheap).
//  - stage-source/read XOR swizzle xq^(q<<1) (both-sides involution) ->
//    2-way LDS aliasing on ds_read_b128 (free per m136).
// FIFO discipline per wave: ... S(ch), F(ch), S(ch+1), F(ch+1), S(ch+2) ...
// pack(F(ch)) implies S(ch) done; explicit vmcnt(4) leaves only S(ch+1) in
// flight at barrier1; stage(ch+2) issues after barrier2 (all readers done).

namespace {
constexpr int B_ = 8, C_ = 256, H_ = 64, W_ = 128;
constexpr int SIDE = 9, ND = 81, PAD = 4;
constexpr int HW = H_ * W_;
constexpr int KC = 32, NCH = C_ / KC;       // 8 chunks of 32 channels
constexpr int YB = 8, RWS = YB + 2 * PAD;   // 16 staged f2 rows
constexpr int XB = 16;
constexpr int NQ = 4;                       // channel-octs per chunk
constexpr int YP_ = H_ + 2 * PAD;           // 72
constexpr int XP_ = 144;                    // padded x (x+4), 144 for tile reach
constexpr size_t ROWU = (size_t)NQ * XP_;   // 576 uint4 per (b,cs,yp)
constexpr size_t PERB = (size_t)NCH * YP_ * ROWU;  // 331,776
constexpr size_t NW2 = (size_t)B_ * PERB;          // 2,654,208 uint4
constexpr size_t WS_BYTES = NW2 * 16;              // 42.5 MB
constexpr int TILE_U4 = RWS * NQ * 32;             // 2048 uint4 = 32 KB
}

typedef __attribute__((ext_vector_type(8))) short short8;
typedef __attribute__((ext_vector_type(4))) float float4v;
typedef __attribute__((address_space(1))) void gvoid;
typedef __attribute__((address_space(3))) void svoid;

__device__ __forceinline__ unsigned bf16rne(float f) {
  unsigned u = __float_as_uint(f);
  return (u + 0x7fffu + ((u >> 16) & 1u)) >> 16;
}
__device__ __forceinline__ unsigned packbf2(float lo, float hi) {
  return bf16rne(lo) | (bf16rne(hi) << 16);
}

// ------- pass 1: f2 fp32 -> fragment-ready bf16 w2, XCD-swizzled -------
__global__ __launch_bounds__(256)
void cvt_f2(const float* __restrict__ f2, uint4* __restrict__ w2) {
  const int id = blockIdx.x;
  const int b = id & 7;                          // XCD pin
  const int e = (id >> 3) * 256 + (int)threadIdx.x;  // 0..PERB-1
  const int xp = e % XP_;
  int r = e / XP_;
  const int q = r & 3;
  r >>= 2;
  const int yp = r % YP_;
  const int cs = r / YP_;
  const int yg = yp - PAD, xg = xp - PAD;
  uint4 o = {0u, 0u, 0u, 0u};
  if (yg >= 0 && yg < H_ && xg >= 0 && xg < W_) {
    const float* s = f2 + ((size_t)(b * C_ + cs * KC + q * 8) * H_ + yg) * W_ + xg;
    o.x = packbf2(s[0 * HW], s[1 * HW]);
    o.y = packbf2(s[2 * HW], s[3 * HW]);
    o.z = packbf2(s[4 * HW], s[5 * HW]);
    o.w = packbf2(s[6 * HW], s[7 * HW]);
  }
  w2[(size_t)b * PERB + e] = o;
}

// ------- pass 2: banded MFMA, LDS-DMA double-buffered chunk pipeline -------
__global__ __launch_bounds__(512, 4)
void corr_mfma2(const float* __restrict__ f1, const uint4* __restrict__ w2,
                float* __restrict__ out) {
  __shared__ uint4 f2s[2 * TILE_U4];             // 64 KB, two 32 KB buffers

  const int id = blockIdx.x;
  const int b = id & 7;                          // XCD pin (matches cvt)
  const int k = id >> 3;                         // 0..63
  const int xg = k & 7, yg = k >> 3;             // xg fast: neighbors share rows
  const int x0 = xg * XB, y0 = yg * YB;

  const int t = threadIdx.x, lane = t & 63, w = t >> 6;  // wave -> y row y0+w
  const int v = lane & 15, q = lane >> 4;
  const int sq = q << 1;                         // read-side XOR swizzle
  const int l_hi = lane >> 5;                    // staging lane geometry
  const int l_xq = lane & 31;

  const uint4* w2b = w2 + (size_t)b * PERB;
  const float* f1b = f1 + (size_t)b * C_ * HW;

  // 4 global_load_lds per wave per chunk: instr kk covers row r=2w+(kk>>1),
  // q-pair qp=kk&1; lane -> qq=2qp+(lane>>5), col slot xq=lane&31, source
  // column x0 + (xq ^ (qq<<1)) (pre-swizzled global addr, linear LDS dest).
  auto issue_stage = [&](int ch, int buf) {
    const uint4* wc = w2b + (size_t)ch * ((size_t)YP_ * ROWU);
#pragma unroll
    for (int kk = 0; kk < 4; ++kk) {
      const int r = 2 * w + (kk >> 1);
      const int qp = kk & 1;
      const int qq = 2 * qp + l_hi;
      const int xqs = l_xq ^ (qq << 1);
      const uint4* gp = wc + (size_t)(y0 + r) * ROWU + (size_t)qq * XP_ + x0 + xqs;
      uint4* lp = &f2s[buf * TILE_U4 + (r * NQ + qp * 2) * 32];
      __builtin_amdgcn_global_load_lds((gvoid*)gp, (svoid*)lp, 16, 0, 0);
    }
  };
  auto issue_f1 = [&](int ch, float* p) {
    const float* fp =
        f1b + ((size_t)(ch * KC + q * 8) * H_ + (y0 + w)) * W_ + x0 + v;
#pragma unroll
    for (int j = 0; j < 8; ++j) p[j] = fp[(size_t)j * HW];
  };

  float4v acc[SIDE][2];
#pragma unroll
  for (int i = 0; i < SIDE; ++i) {
    acc[i][0] = (float4v){0.f, 0.f, 0.f, 0.f};
    acc[i][1] = (float4v){0.f, 0.f, 0.f, 0.f};
  }

  float p0[8], p1[8];
  issue_stage(0, 0);
  __builtin_amdgcn_sched_barrier(0);
  issue_f1(0, p0);
  __builtin_amdgcn_sched_barrier(0);
  issue_stage(1, 1);
  __builtin_amdgcn_sched_barrier(0);

#pragma unroll
  for (int ch = 0; ch < NCH; ++ch) {
    float* pc = (ch & 1) ? p1 : p0;              // ch literal under unroll
    uint4 afu;
    afu.x = packbf2(pc[0], pc[1]);
    afu.y = packbf2(pc[2], pc[3]);
    afu.z = packbf2(pc[4], pc[5]);
    afu.w = packbf2(pc[6], pc[7]);
    const short8 af = __builtin_bit_cast(short8, afu);

    // stage(ch) done (4 newest in flight = stage(ch+1)); NEVER drain to 0.
    asm volatile("s_waitcnt vmcnt(4)" ::: "memory");
    __builtin_amdgcn_s_barrier();
    __builtin_amdgcn_sched_barrier(0);

    if (ch + 1 < NCH) issue_f1(ch + 1, (ch & 1) ? p0 : p1);

    const int bo = (ch & 1) * TILE_U4;
#pragma unroll
    for (int dy = 0; dy < SIDE; ++dy) {
      const uint4* base = &f2s[bo + ((w + dy) * NQ + q) * 32];
      const short8 b0 = __builtin_bit_cast(short8, base[v ^ sq]);
      const short8 b1 = __builtin_bit_cast(short8, base[(v + 16) ^ sq]);
      acc[dy][0] =
          __builtin_amdgcn_mfma_f32_16x16x32_bf16(af, b0, acc[dy][0], 0, 0, 0);
      acc[dy][1] =
          __builtin_amdgcn_mfma_f32_16x16x32_bf16(af, b1, acc[dy][1], 0, 0, 0);
    }
    __builtin_amdgcn_sched_barrier(0);
    __builtin_amdgcn_s_barrier();                // all readers of buf done
    __builtin_amdgcn_sched_barrier(0);
    if (ch + 2 < NCH) issue_stage(ch + 2, ch & 1);  // overwrite after barrier
  }

  // Epilogue: C/D col n = v, row m = q*4+r. tile0: dx = v-m in [0,8];
  // tile1: dx = v-m+16 in [1,8]. Each output element written exactly once.
  const int y = y0 + w;
  float* outb = out + (size_t)b * ND * HW + (size_t)y * W_ + x0;
#pragma unroll
  for (int dy = 0; dy < SIDE; ++dy) {
#pragma unroll
    for (int r = 0; r < 4; ++r) {
      const int m = q * 4 + r;
      const int dx0 = v - m;
      if (dx0 >= 0 && dx0 <= 8)
        outb[(size_t)(dy * SIDE + dx0) * HW + m] = acc[dy][0][r];
      const int dx1 = v - m + 16;
      if (dx1 <= 8)
        outb[(size_t)(dy * SIDE + dx1) * HW + m] = acc[dy][1][r];
    }
  }
}

// ---------------- fallback (R10 fused kernel, proven) if ws too small ------
namespace fb {
constexpr int PXS = 20, F2PX = 32, F2U = 16 * (F2PX / 4) * 16;
}

__global__ __launch_bounds__(512, 4)
void corr_fb(const float* __restrict__ f1, const float* __restrict__ f2,
             float* __restrict__ out) {
  using namespace fb;
  __shared__ __align__(16) unsigned f2s[RWS * F2PX * PXS];
  __shared__ __align__(16) unsigned f1s[YB * XB * PXS];

  const int id = blockIdx.x;
  const int b = id & 7;
  const int k = id >> 3;
  const int xg = k & 7, yg = k >> 3;
  const int x0 = xg * XB, y0 = yg * YB;
  const int t = threadIdx.x, lane = t & 63, w = t >> 6;
  const int v = lane & 15, q = lane >> 4;

  float4v acc[SIDE][2];
#pragma unroll
  for (int i = 0; i < SIDE; ++i) {
    acc[i][0] = (float4v){0.f, 0.f, 0.f, 0.f};
    acc[i][1] = (float4v){0.f, 0.f, 0.f, 0.f};
  }
  const float* __restrict__ f1b = f1 + (size_t)b * C_ * HW;
  const float* __restrict__ f2b = f2 + (size_t)b * C_ * HW;

  for (int ch = 0; ch < NCH; ++ch) {
    const int c0 = ch * KC;
    if (ch) __syncthreads();
#pragma unroll
    for (int u0 = 0; u0 < F2U; u0 += 512) {
      const int u = u0 + t;
      const int cp = u & 15;
      const int t2 = u >> 4;
      const int pxq = t2 & 7;
      const int r = t2 >> 3;
      const int ygl = y0 - PAD + r;
      const int xb = x0 - PAD + pxq * 4;
      float4 va = make_float4(0.f, 0.f, 0.f, 0.f), vb = va;
      if (ygl >= 0 && ygl < H_ && xb >= 0 && xb <= W_ - 4) {
        const float* p = f2b + ((size_t)(c0 + 2 * cp) * H_ + ygl) * W_ + xb;
        va = *(const float4*)p;
        vb = *(const float4*)(p + HW);
      }
      unsigned* d = &f2s[(r * F2PX + pxq * 4) * PXS + cp];
      d[0 * PXS] = packbf2(va.x, vb.x);
      d[1 * PXS] = packbf2(va.y, vb.y);
      d[2 * PXS] = packbf2(va.z, vb.z);
      d[3 * PXS] = packbf2(va.w, vb.w);
    }
    {
      const int cp = t & 15;
      const int t2 = t >> 4;
      const int pxq = t2 & 3;
      const int r = t2 >> 2;
      const float* p =
          f1b + ((size_t)(c0 + 2 * cp) * H_ + (y0 + r)) * W_ + x0 + pxq * 4;
      const float4 va = *(const float4*)p;
      const float4 vb = *(const float4*)(p + HW);
      unsigned* d = &f1s[(r * XB + pxq * 4) * PXS + cp];
      d[0 * PXS] = packbf2(va.x, vb.x);
      d[1 * PXS] = packbf2(va.y, vb.y);
      d[2 * PXS] = packbf2(va.z, vb.z);
      d[3 * PXS] = packbf2(va.w, vb.w);
    }
    __syncthreads();

    const short8 af = __builtin_bit_cast(
        short8, *(const uint4*)&f1s[(w * XB + v) * PXS + 4 * q]);
#pragma unroll
    for (int dy = 0; dy < SIDE; ++dy) {
      const unsigned* fp = &f2s[((w + dy) * F2PX + v) * PXS + 4 * q];
      const short8 b0 = __builtin_bit_cast(short8, *(const uint4*)fp);
      const short8 b1 =
          __builtin_bit_cast(short8, *(const uint4*)(fp + 16 * PXS));
      acc[dy][0] =
          __builtin_amdgcn_mfma_f32_16x16x32_bf16(af, b0, acc[dy][0], 0, 0, 0);
      acc[dy][1] =
          __builtin_amdgcn_mfma_f32_16x16x32_bf16(af, b1, acc[dy][1], 0, 0, 0);
    }
  }
  const int y = y0 + w;
  float* outb = out + (size_t)b * ND * HW + (size_t)y * W_ + x0;
#pragma unroll
  for (int dy = 0; dy < SIDE; ++dy) {
#pragma unroll
    for (int r = 0; r < 4; ++r) {
      const int m = q * 4 + r;
      const int dx0 = v - m;
      if (dx0 >= 0 && dx0 <= 8)
        outb[(size_t)(dy * SIDE + dx0) * HW + m] = acc[dy][0][r];
      const int dx1 = v - m + 16;
      if (dx1 <= 8)
        outb[(size_t)(dy * SIDE + dx1) * HW + m] = acc[dy][1][r];
    }
  }
}

extern "C" void kernel_launch(void* const* d_in, const int* in_sizes, int n_in,
                              void* d_out, int out_size, void* d_ws,
                              size_t ws_size, hipStream_t stream) {
  (void)in_sizes; (void)n_in; (void)out_size;
  const float* f1 = (const float*)d_in[0];
  const float* f2 = (const float*)d_in[1];
  float* out = (float*)d_out;
  if (ws_size >= WS_BYTES) {
    uint4* w2 = (uint4*)d_ws;
    cvt_f2<<<dim3((unsigned)(NW2 / 256)), 256, 0, stream>>>(f2, w2);
    corr_mfma2<<<dim3(512), 512, 0, stream>>>(f1, w2, out);
  } else {
    corr_fb<<<dim3(512), 512, 0, stream>>>(f1, f2, out);
  }
}